// Round 7
// baseline (682.749 us; speedup 1.0000x reference)
//
#include <hip/hip_runtime.h>
#include <hip/hip_bf16.h>

// Problem constants (B=2, S=2048, D=2048, H=16, HD=128)
#define Bv 2
#define Sv 2048
#define Dv 2048
#define Hv 16
#define HDv 128

typedef short bf16x8 __attribute__((ext_vector_type(8)));
typedef float f32x4 __attribute__((ext_vector_type(4)));

__device__ inline float b2f(unsigned short u) {
  union { unsigned int i; float f; } x; x.i = ((unsigned int)u) << 16; return x.f;
}
__device__ inline unsigned short f2b(float f) {
  union { float f; unsigned int u; } x; x.f = f;
  unsigned int r = (x.u + 0x7fffu + ((x.u >> 16) & 1u)) >> 16;  // RNE
  return (unsigned short)r;
}

#define GLL16(gsrc, ldst)                                                      \
  __builtin_amdgcn_global_load_lds(                                            \
      (__attribute__((address_space(1))) void*)(gsrc),                         \
      (__attribute__((address_space(3))) void*)(ldst), 16, 0, 0)

// ---------------- f32 -> bf16 convert (vectorized) ----------------
__global__ __launch_bounds__(256) void f2b_kernel(const float4* __restrict__ in,
                                                  ushort4* __restrict__ out, int n4) {
  int i = blockIdx.x * 256 + threadIdx.x;
  if (i >= n4) return;
  float4 v = in[i];
  ushort4 r;
  r.x = f2b(v.x); r.y = f2b(v.y); r.z = f2b(v.z); r.w = f2b(v.w);
  out[i] = r;
}

// ---------------- W [K][N] f32 -> WT [N][K] bf16 (transpose-convert) ----------------
__global__ void wtrans_kernel(const float* __restrict__ W, short* __restrict__ WT) {
  __shared__ float tile[32][33];
  int tx = threadIdx.x, ty = threadIdx.y;        // 32 x 8
  int c0 = blockIdx.x * 32, r0 = blockIdx.y * 32;
#pragma unroll
  for (int i = 0; i < 4; i++)
    tile[ty + i * 8][tx] = W[(long)(r0 + ty + i * 8) * Dv + c0 + tx];
  __syncthreads();
#pragma unroll
  for (int i = 0; i < 4; i++)
    WT[(long)(c0 + ty + i * 8) * Dv + r0 + tx] = (short)f2b(tile[tx][ty + i * 8]);
}

// ---------------- V [bh][key][d] bf16 -> VT [bh][d][key] bf16 ----------------
__global__ void vtrans_kernel(const short* __restrict__ V, short* __restrict__ VT) {
  __shared__ short tile[32][33];
  int tx = threadIdx.x, ty = threadIdx.y;        // 32 x 8
  int k0 = blockIdx.x * 32, d0 = blockIdx.y * 32, bh = blockIdx.z;
  const short* src = V + (long)bh * Sv * HDv;
  short* dst = VT + (long)bh * HDv * Sv;
#pragma unroll
  for (int i = 0; i < 4; i++)
    tile[ty + i * 8][tx] = src[(long)(k0 + ty + i * 8) * HDv + d0 + tx];
  __syncthreads();
#pragma unroll
  for (int i = 0; i < 4; i++)
    dst[(long)(d0 + ty + i * 8) * Sv + k0 + tx] = tile[tx][ty + i * 8];
}

// ---------------- RoPE cos/sin table: tab[s*128 + d]=cos, +64=sin (d<64) ----------------
__global__ __launch_bounds__(256) void rope_table_kernel(float* __restrict__ tab) {
  int i = blockIdx.x * 256 + threadIdx.x;  // 0 .. S*64-1
  int s = i >> 6, d = i & 63;
  float inv = powf(10000.f, -(float)d * (1.f / 64.f));
  float ang = (float)s * inv;
  tab[s * 128 + d] = cosf(ang);
  tab[s * 128 + 64 + d] = sinf(ang);
}

// ---------------- RoPE apply in-place on Q and K (contiguous, 2*B*H*S rows) ----------------
__global__ __launch_bounds__(256) void rope_kernel(short* __restrict__ T,
                                                   const float* __restrict__ tab) {
  int tid = blockIdx.x * 256 + threadIdx.x;   // 2*B*H*S*8 threads, 8 per row
  int r = tid >> 3, j = tid & 7;
  int s = r & (Sv - 1);
  short* p = T + (long)r * HDv + j * 8;
  bf16x8 a = *(const bf16x8*)p;
  bf16x8 bb = *(const bf16x8*)(p + 64);
  const float* tc = tab + s * 128 + j * 8;
  float4 c0 = *(const float4*)tc, c1 = *(const float4*)(tc + 4);
  float4 s0 = *(const float4*)(tc + 64), s1 = *(const float4*)(tc + 68);
  float cs[8] = {c0.x, c0.y, c0.z, c0.w, c1.x, c1.y, c1.z, c1.w};
  float sn[8] = {s0.x, s0.y, s0.z, s0.w, s1.x, s1.y, s1.z, s1.w};
  bf16x8 na, nb;
#pragma unroll
  for (int e = 0; e < 8; e++) {
    float x1 = b2f((unsigned short)a[e]);
    float x2 = b2f((unsigned short)bb[e]);
    na[e] = (short)f2b(x1 * cs[e] - x2 * sn[e]);
    nb[e] = (short)f2b(x2 * cs[e] + x1 * sn[e]);
  }
  *(bf16x8*)p = na;
  *(bf16x8*)(p + 64) = nb;
}

// ---------------- bf16 MFMA GEMM: C = A[M][K] * Bt[N][K]^T ----------------
// MODE 0: write bf16 QKV with [3][B][H][S][HD] scatter; MODE 1: write f32 row-major
template <int MODE>
__global__ __launch_bounds__(256) void gemm_kernel(const short* __restrict__ A,
                                                   const short* __restrict__ Bt,
                                                   void* __restrict__ Cout,
                                                   int M, int N, int K) {
  __shared__ __align__(16) short As[128 * 32];
  __shared__ __align__(16) short Bs[128 * 32];
  const int t = threadIdx.x, w = t >> 6, l = t & 63;
  const int m0 = blockIdx.y * 128, n0 = blockIdx.x * 128;
  const int wr = w >> 1, wc = w & 1;
  f32x4 acc[4][4] = {};
  const short* ag = A + (long)(m0 + (t >> 2)) * K + (t & 3) * 8;
  const short* bg = Bt + (long)(n0 + (t >> 2)) * K + (t & 3) * 8;
  short* asw = As + (w * 16) * 32;   // wave-uniform LDS staging base
  short* bsw = Bs + (w * 16) * 32;
  const int aoff = (wr * 64 + (l & 15)) * 32 + (l >> 4) * 8;
  const int boff = (wc * 64 + (l & 15)) * 32 + (l >> 4) * 8;
  for (int k0 = 0; k0 < K; k0 += 32) {
    GLL16(ag + k0, asw);
    GLL16(ag + (long)64 * K + k0, asw + 64 * 32);
    GLL16(bg + k0, bsw);
    GLL16(bg + (long)64 * K + k0, bsw + 64 * 32);
    __syncthreads();
    bf16x8 af[4], bf[4];
#pragma unroll
    for (int i = 0; i < 4; i++) af[i] = *(const bf16x8*)(As + aoff + i * 16 * 32);
#pragma unroll
    for (int i = 0; i < 4; i++) bf[i] = *(const bf16x8*)(Bs + boff + i * 16 * 32);
#pragma unroll
    for (int i = 0; i < 4; i++)
#pragma unroll
      for (int j = 0; j < 4; j++)
        acc[i][j] = __builtin_amdgcn_mfma_f32_16x16x32_bf16(af[i], bf[j], acc[i][j], 0, 0, 0);
    __syncthreads();
  }
  // epilogue: C/D layout col = lane&15, row = (lane>>4)*4 + j  [m89-verified]
  const int fr = l >> 4;
#pragma unroll
  for (int mi = 0; mi < 4; mi++) {
#pragma unroll
    for (int ni = 0; ni < 4; ni++) {
      f32x4 v = acc[mi][ni];
      int col = n0 + wc * 64 + ni * 16 + (l & 15);
      int mbase = m0 + wr * 64 + mi * 16 + fr * 4;
      if (MODE == 0) {
        short* qkv = (short*)Cout;
        int which = col >> 11, hn = col & 2047;
        int h = hn >> 7, d = hn & 127;
#pragma unroll
        for (int j = 0; j < 4; j++) {
          int m = mbase + j;
          int b = m >> 11, s = m & 2047;
          qkv[(long)which * 8388608 + (((long)(b * Hv + h)) * Sv + s) * HDv + d] =
              (short)f2b(v[j]);
        }
      } else {
        float* C = (float*)Cout;
#pragma unroll
        for (int j = 0; j < 4; j++) C[(long)(mbase + j) * N + col] = v[j];
      }
    }
  }
}

// ---------------- MFMA flash attention ----------------
// 4 waves/block; wave owns 16 q-rows (64 q/block), KVBLK=64. Heavy-first qb order.
// k_s  [64][128]: K rows, GLL16 w/ pre-swizzled src, XOR key (row&15)<<3.
// vt_s [64][128]: packed V^T (row r = d=r keys0..63 | d=r+64 keys0..63), GLL16 same swizzle.
// p_s  [4][16][64]: per-wave P round-trip, XOR key (q_loc&7)<<3.
// LDS total = 16384 + 16384 + 8192 = 40960 B -> 4 blocks/CU.
__global__ __launch_bounds__(256) void attn_kernel(const short* __restrict__ Q,
                                                   const short* __restrict__ Kk,
                                                   const short* __restrict__ VT,
                                                   short* __restrict__ O) {
  __shared__ __align__(16) short k_s[64 * 128];
  __shared__ __align__(16) short vt_s[64 * 128];
  __shared__ __align__(16) short p_s[4 * 16 * 64];
  const int t = threadIdx.x, w = t >> 6, l = t & 63;
  const int g = l >> 4, a = l & 15;
  const int bh = blockIdx.y;
  const int qb = (gridDim.x - 1) - blockIdx.x;   // heavy-first (LPT) ordering
  const int q0w = qb * 64 + w * 16;
  const short* Qb = Q + (long)bh * Sv * HDv;
  const short* Kb = Kk + (long)bh * Sv * HDv;
  const short* VTb = VT + (long)bh * HDv * Sv;   // [d][key]

  bf16x8 qf[4];
#pragma unroll
  for (int kk = 0; kk < 4; kk++)
    qf[kk] = *(const bf16x8*)(Qb + (long)(q0w + a) * HDv + kk * 32 + g * 8);

  f32x4 acc_o[8] = {};                       // O[16q][128d]: 8 d-blocks of 16
  float m_run[4] = {-1e30f, -1e30f, -1e30f, -1e30f};
  float l_run[4] = {0.f, 0.f, 0.f, 0.f};
  const float scale = 0.08838834764831845f;  // 1/sqrt(128)

  // staging lane decomposition (same for K and VT): rr = l>>4 row-in-group,
  // sub = l&15 16B chunk; physical elem p0 = sub*8; logical col c0 = p0 ^ key(row)
  const int rr = l >> 4, sub = l & 15;

  for (int kb = 0; kb <= qb; ++kb) {
    const int kv0 = kb * 64;
    __syncthreads();
    // ---- stage K tile [64 keys][128 d] ----
#pragma unroll
    for (int j = 0; j < 4; j++) {
      int row = j * 16 + w * 4 + rr;           // key row
      int c0 = (sub * 8) ^ ((row & 15) << 3);  // logical d-offset
      GLL16(Kb + (long)(kv0 + row) * HDv + c0, k_s + (j * 16 + w * 4) * 128);
    }
    // ---- stage packed V^T tile [64 rows][128] (row r: d=r | d=r+64, keys kv0..+63) ----
#pragma unroll
    for (int j = 0; j < 4; j++) {
      int row = w * 16 + j * 4 + rr;
      int c0 = (sub * 8) ^ ((row & 15) << 3);
      int d = row + (c0 & 64);
      GLL16(VTb + (long)d * Sv + kv0 + (c0 & 63), vt_s + (w * 16 + j * 4) * 128);
    }
    __syncthreads();
    // ---- QK^T: S[16q][64k] ----
    f32x4 sacc[4] = {};
#pragma unroll
    for (int ksb = 0; ksb < 4; ksb++) {
      int row = ksb * 16 + a;
#pragma unroll
      for (int kk = 0; kk < 4; kk++) {
        bf16x8 kf = *(const bf16x8*)(k_s + row * 128 + ((kk * 32 + g * 8) ^ ((row & 15) << 3)));
        sacc[ksb] = __builtin_amdgcn_mfma_f32_16x16x32_bf16(qf[kk], kf, sacc[ksb], 0, 0, 0);
      }
    }
    // ---- online softmax (rows q = q0w + g*4 + r; cols key = kv0 + ksb*16 + a) ----
    float s[4][4];
    const bool domask = (kb == qb);
#pragma unroll
    for (int ksb = 0; ksb < 4; ksb++)
#pragma unroll
      for (int r = 0; r < 4; r++) {
        float v = sacc[ksb][r] * scale;
        if (domask) {
          int key = kv0 + ksb * 16 + a, qq = q0w + g * 4 + r;
          v = (key <= qq) ? v : -1e30f;
        }
        s[ksb][r] = v;
      }
    float mnew[4], alpha[4];
#pragma unroll
    for (int r = 0; r < 4; r++) {
      float m = fmaxf(fmaxf(s[0][r], s[1][r]), fmaxf(s[2][r], s[3][r]));
      m = fmaxf(m, __shfl_xor(m, 1));
      m = fmaxf(m, __shfl_xor(m, 2));
      m = fmaxf(m, __shfl_xor(m, 4));
      m = fmaxf(m, __shfl_xor(m, 8));
      mnew[r] = fmaxf(m_run[r], m);
      alpha[r] = __expf(m_run[r] - mnew[r]);
      m_run[r] = mnew[r];
    }
    float rs[4] = {0.f, 0.f, 0.f, 0.f};
#pragma unroll
    for (int ksb = 0; ksb < 4; ksb++)
#pragma unroll
      for (int r = 0; r < 4; r++) {
        float p = __expf(s[ksb][r] - mnew[r]);
        s[ksb][r] = p;
        rs[r] += p;
      }
#pragma unroll
    for (int r = 0; r < 4; r++) {
      float x = rs[r];
      x += __shfl_xor(x, 1);
      x += __shfl_xor(x, 2);
      x += __shfl_xor(x, 4);
      x += __shfl_xor(x, 8);
      l_run[r] = l_run[r] * alpha[r] + x;
    }
    // ---- P -> per-wave LDS (bf16, stride 64 + XOR), re-read in A-fragment layout ----
#pragma unroll
    for (int ksb = 0; ksb < 4; ksb++)
#pragma unroll
      for (int r = 0; r < 4; r++) {
        int q_loc = g * 4 + r;
        p_s[w * 1024 + q_loc * 64 + ((ksb * 16 + a) ^ ((q_loc & 7) << 3))] =
            (short)f2b(s[ksb][r]);
      }
    // ---- rescale O ----
#pragma unroll
    for (int d = 0; d < 8; d++)
#pragma unroll
      for (int r = 0; r < 4; r++) acc_o[d][r] *= alpha[r];
    // ---- PV: O += P[16q][64k] * V[64k][128d] via packed V^T ----
    bf16x8 pa[2];
#pragma unroll
    for (int kc = 0; kc < 2; kc++)
      pa[kc] = *(const bf16x8*)(p_s + w * 1024 + a * 64 + ((kc * 32 + g * 8) ^ ((a & 7) << 3)));
#pragma unroll
    for (int dblk = 0; dblk < 8; dblk++) {
      int row = (dblk & 3) * 16 + a;           // packed row; half = dblk>>2
      int half = (dblk >> 2) * 64;
#pragma unroll
      for (int kc = 0; kc < 2; kc++) {
        bf16x8 vf = *(const bf16x8*)(vt_s + row * 128 +
                                     ((half + kc * 32 + g * 8) ^ ((row & 15) << 3)));
        acc_o[dblk] = __builtin_amdgcn_mfma_f32_16x16x32_bf16(pa[kc], vf, acc_o[dblk], 0, 0, 0);
      }
    }
  }
  // ---- epilogue: O /= l_run, write bf16 [B][S][D] ----
  const int b = bh >> 4, h = bh & 15;
#pragma unroll
  for (int r = 0; r < 4; r++) {
    float inv = 1.f / l_run[r];
    int q = q0w + g * 4 + r;
    short* orow = O + ((long)(b * Sv + q)) * Dv + h * HDv + a;
#pragma unroll
    for (int d = 0; d < 8; d++) orow[d * 16] = (short)f2b(acc_o[d][r] * inv);
  }
}

extern "C" void kernel_launch(void* const* d_in, const int* in_sizes, int n_in,
                              void* d_out, int out_size, void* d_ws, size_t ws_size,
                              hipStream_t stream) {
  // inputs: 0=hidden_states f32, 1=attention_mask (unused: deterministically causal),
  // 2=position_ids (unused: deterministically arange(S)), 3..6 = Wq,Wk,Wv,Wo f32 [K][N]
  const float* X = (const float*)d_in[0];
  const float* Wq = (const float*)d_in[3];
  const float* Wk = (const float*)d_in[4];
  const float* Wv = (const float*)d_in[5];
  const float* Wo = (const float*)d_in[6];
  float* out = (float*)d_out;

  // workspace layout (bf16 stored as short); AO aliases XB (XB dead after GEMM1);
  // VTG aliases WQKVT (dead after gemm<0>)
  short* XB = (short*)d_ws;              // 8,388,608 elems  [B*S][D] bf16
  short* WQKVT = XB + 8388608;           // 12,582,912       [3*D][K] bf16 (transposed)
  short* WOT = WQKVT + 12582912;         // 4,194,304        [D][K] bf16 (transposed)
  short* QKV = WOT + 4194304;            // 25,165,824       3 x [B][H][S][HD] bf16
  float* TAB = (float*)(QKV + 25165824); // 262,144 f32      [S][128] cos|sin
  short* AO = XB;                        // attn out [B][S][D] bf16 (reuse XB)
  short* VTG = WQKVT;                    // V^T [bh][d][key] (reuse WQKVT, 8.4M <= 12.6M)

  f2b_kernel<<<8192, 256, 0, stream>>>((const float4*)X, (ushort4*)XB, 2097152);
  dim3 wtb(32, 8), wtg(64, 64);
  wtrans_kernel<<<wtg, wtb, 0, stream>>>(Wq, WQKVT);
  wtrans_kernel<<<wtg, wtb, 0, stream>>>(Wk, WQKVT + 4194304);
  wtrans_kernel<<<wtg, wtb, 0, stream>>>(Wv, WQKVT + 8388608);
  wtrans_kernel<<<wtg, wtb, 0, stream>>>(Wo, WOT);
  rope_table_kernel<<<512, 256, 0, stream>>>(TAB);
  // QKV projection: M=4096, N=6144, K=2048 -> scatter to [3][B][H][S][HD]
  gemm_kernel<0><<<dim3(48, 32), 256, 0, stream>>>(XB, WQKVT, QKV, 4096, 6144, 2048);
  rope_kernel<<<4096, 256, 0, stream>>>(QKV, TAB);  // Q and K in one launch
  // V -> V^T (WQKVT region is dead after gemm<0>)
  vtrans_kernel<<<dim3(64, 4, 32), wtb, 0, stream>>>(QKV + 16777216, VTG);
  attn_kernel<<<dim3(32, 32), 256, 0, stream>>>(QKV, QKV + 8388608, VTG, AO);
  // output projection -> f32 d_out
  gemm_kernel<1><<<dim3(16, 32), 256, 0, stream>>>(AO, WOT, out, 4096, 2048, 2048);
}

// Round 8
// 512.451 us; speedup vs baseline: 1.3323x; 1.3323x over previous
//
#include <hip/hip_runtime.h>
#include <hip/hip_bf16.h>

// Problem constants (B=2, S=2048, D=2048, H=16, HD=128)
#define Bv 2
#define Sv 2048
#define Dv 2048
#define Hv 16
#define HDv 128

typedef short bf16x8 __attribute__((ext_vector_type(8)));
typedef float f32x4 __attribute__((ext_vector_type(4)));

__device__ inline float b2f(unsigned short u) {
  union { unsigned int i; float f; } x; x.i = ((unsigned int)u) << 16; return x.f;
}
__device__ inline unsigned short f2b(float f) {
  union { float f; unsigned int u; } x; x.f = f;
  unsigned int r = (x.u + 0x7fffu + ((x.u >> 16) & 1u)) >> 16;  // RNE
  return (unsigned short)r;
}

#define GLL16(gsrc, ldst)                                                      \
  __builtin_amdgcn_global_load_lds(                                            \
      (__attribute__((address_space(1))) void*)(gsrc),                         \
      (__attribute__((address_space(3))) void*)(ldst), 16, 0, 0)

// ---------------- f32 -> bf16 convert (vectorized) ----------------
__global__ __launch_bounds__(256) void f2b_kernel(const float4* __restrict__ in,
                                                  ushort4* __restrict__ out, int n4) {
  int i = blockIdx.x * 256 + threadIdx.x;
  if (i >= n4) return;
  float4 v = in[i];
  ushort4 r;
  r.x = f2b(v.x); r.y = f2b(v.y); r.z = f2b(v.z); r.w = f2b(v.w);
  out[i] = r;
}

// ---------------- W [K][N] f32 -> WT [N][K] bf16 (transpose-convert) ----------------
__global__ void wtrans_kernel(const float* __restrict__ W, short* __restrict__ WT) {
  __shared__ float tile[32][33];
  int tx = threadIdx.x, ty = threadIdx.y;        // 32 x 8
  int c0 = blockIdx.x * 32, r0 = blockIdx.y * 32;
#pragma unroll
  for (int i = 0; i < 4; i++)
    tile[ty + i * 8][tx] = W[(long)(r0 + ty + i * 8) * Dv + c0 + tx];
  __syncthreads();
#pragma unroll
  for (int i = 0; i < 4; i++)
    WT[(long)(c0 + ty + i * 8) * Dv + r0 + tx] = (short)f2b(tile[tx][ty + i * 8]);
}

// ---------------- V [bh][key][d] bf16 -> VT [bh][d][key] bf16 ----------------
__global__ void vtrans_kernel(const short* __restrict__ V, short* __restrict__ VT) {
  __shared__ short tile[32][33];
  int tx = threadIdx.x, ty = threadIdx.y;        // 32 x 8
  int k0 = blockIdx.x * 32, d0 = blockIdx.y * 32, bh = blockIdx.z;
  const short* src = V + (long)bh * Sv * HDv;
  short* dst = VT + (long)bh * HDv * Sv;
#pragma unroll
  for (int i = 0; i < 4; i++)
    tile[ty + i * 8][tx] = src[(long)(k0 + ty + i * 8) * HDv + d0 + tx];
  __syncthreads();
#pragma unroll
  for (int i = 0; i < 4; i++)
    dst[(long)(d0 + ty + i * 8) * Sv + k0 + tx] = tile[tx][ty + i * 8];
}

// ---------------- RoPE cos/sin table: tab[s*128 + d]=cos, +64=sin (d<64) ----------------
__global__ __launch_bounds__(256) void rope_table_kernel(float* __restrict__ tab) {
  int i = blockIdx.x * 256 + threadIdx.x;  // 0 .. S*64-1
  int s = i >> 6, d = i & 63;
  float inv = powf(10000.f, -(float)d * (1.f / 64.f));
  float ang = (float)s * inv;
  tab[s * 128 + d] = cosf(ang);
  tab[s * 128 + 64 + d] = sinf(ang);
}

// ---------------- RoPE apply in-place on Q and K (contiguous, 2*B*H*S rows) ----------------
__global__ __launch_bounds__(256) void rope_kernel(short* __restrict__ T,
                                                   const float* __restrict__ tab) {
  int tid = blockIdx.x * 256 + threadIdx.x;   // 2*B*H*S*8 threads, 8 per row
  int r = tid >> 3, j = tid & 7;
  int s = r & (Sv - 1);
  short* p = T + (long)r * HDv + j * 8;
  bf16x8 a = *(const bf16x8*)p;
  bf16x8 bb = *(const bf16x8*)(p + 64);
  const float* tc = tab + s * 128 + j * 8;
  float4 c0 = *(const float4*)tc, c1 = *(const float4*)(tc + 4);
  float4 s0 = *(const float4*)(tc + 64), s1 = *(const float4*)(tc + 68);
  float cs[8] = {c0.x, c0.y, c0.z, c0.w, c1.x, c1.y, c1.z, c1.w};
  float sn[8] = {s0.x, s0.y, s0.z, s0.w, s1.x, s1.y, s1.z, s1.w};
  bf16x8 na, nb;
#pragma unroll
  for (int e = 0; e < 8; e++) {
    float x1 = b2f((unsigned short)a[e]);
    float x2 = b2f((unsigned short)bb[e]);
    na[e] = (short)f2b(x1 * cs[e] - x2 * sn[e]);
    nb[e] = (short)f2b(x2 * cs[e] + x1 * sn[e]);
  }
  *(bf16x8*)p = na;
  *(bf16x8*)(p + 64) = nb;
}

// ---------------- bf16 MFMA GEMM: C = A[M][K] * Bt[N][K]^T ----------------
// MODE 0: write bf16 QKV with [3][B][H][S][HD] scatter; MODE 1: write f32 row-major
template <int MODE>
__global__ __launch_bounds__(256) void gemm_kernel(const short* __restrict__ A,
                                                   const short* __restrict__ Bt,
                                                   void* __restrict__ Cout,
                                                   int M, int N, int K) {
  __shared__ __align__(16) short As[128 * 32];
  __shared__ __align__(16) short Bs[128 * 32];
  const int t = threadIdx.x, w = t >> 6, l = t & 63;
  const int m0 = blockIdx.y * 128, n0 = blockIdx.x * 128;
  const int wr = w >> 1, wc = w & 1;
  f32x4 acc[4][4] = {};
  const short* ag = A + (long)(m0 + (t >> 2)) * K + (t & 3) * 8;
  const short* bg = Bt + (long)(n0 + (t >> 2)) * K + (t & 3) * 8;
  short* asw = As + (w * 16) * 32;   // wave-uniform LDS staging base
  short* bsw = Bs + (w * 16) * 32;
  const int aoff = (wr * 64 + (l & 15)) * 32 + (l >> 4) * 8;
  const int boff = (wc * 64 + (l & 15)) * 32 + (l >> 4) * 8;
  for (int k0 = 0; k0 < K; k0 += 32) {
    GLL16(ag + k0, asw);
    GLL16(ag + (long)64 * K + k0, asw + 64 * 32);
    GLL16(bg + k0, bsw);
    GLL16(bg + (long)64 * K + k0, bsw + 64 * 32);
    __syncthreads();
    bf16x8 af[4], bf[4];
#pragma unroll
    for (int i = 0; i < 4; i++) af[i] = *(const bf16x8*)(As + aoff + i * 16 * 32);
#pragma unroll
    for (int i = 0; i < 4; i++) bf[i] = *(const bf16x8*)(Bs + boff + i * 16 * 32);
#pragma unroll
    for (int i = 0; i < 4; i++)
#pragma unroll
      for (int j = 0; j < 4; j++)
        acc[i][j] = __builtin_amdgcn_mfma_f32_16x16x32_bf16(af[i], bf[j], acc[i][j], 0, 0, 0);
    __syncthreads();
  }
  // epilogue: C/D layout col = lane&15, row = (lane>>4)*4 + j  [m89-verified]
  const int fr = l >> 4;
#pragma unroll
  for (int mi = 0; mi < 4; mi++) {
#pragma unroll
    for (int ni = 0; ni < 4; ni++) {
      f32x4 v = acc[mi][ni];
      int col = n0 + wc * 64 + ni * 16 + (l & 15);
      int mbase = m0 + wr * 64 + mi * 16 + fr * 4;
      if (MODE == 0) {
        short* qkv = (short*)Cout;
        int which = col >> 11, hn = col & 2047;
        int h = hn >> 7, d = hn & 127;
#pragma unroll
        for (int j = 0; j < 4; j++) {
          int m = mbase + j;
          int b = m >> 11, s = m & 2047;
          qkv[(long)which * 8388608 + (((long)(b * Hv + h)) * Sv + s) * HDv + d] =
              (short)f2b(v[j]);
        }
      } else {
        float* C = (float*)Cout;
#pragma unroll
        for (int j = 0; j < 4; j++) C[(long)(mbase + j) * N + col] = v[j];
      }
    }
  }
}

// ---------------- MFMA flash attention, 2-phase pipelined ----------------
// 4 waves/block; wave owns 32 q-rows (2 subtiles of 16), QBLK=128/block, KVBLK=64.
// Double-buffered K and packed-V^T tiles; next tile's GLL16s issue BEFORE compute,
// counted vmcnt(8) (never 0 mid-loop) + raw s_barrier. LDS 80 KB -> 2 blocks/CU.
// qb pairing: (bh>>4)&1 flips x ordering so co-resident blocks sum to ~const work.
__global__ __launch_bounds__(256, 2) void attn_kernel(const short* __restrict__ Q,
                                                      const short* __restrict__ Kk,
                                                      const short* __restrict__ VT,
                                                      short* __restrict__ O) {
  __shared__ __align__(16) short k_s[2][64 * 128];
  __shared__ __align__(16) short vt_s[2][64 * 128];
  __shared__ __align__(16) short p_s[4][2][16 * 64];
  const int t = threadIdx.x, w = t >> 6, l = t & 63;
  const int g = l >> 4, a = l & 15;
  const int bh = blockIdx.y;
  const int qb = ((bh >> 4) & 1) ? blockIdx.x : (15 - blockIdx.x);
  const int q0 = qb * 128;
  const short* Qb = Q + (long)bh * Sv * HDv;
  const short* Kb = Kk + (long)bh * Sv * HDv;
  const short* VTb = VT + (long)bh * HDv * Sv;   // [d][key]
  const int rr = l >> 4, sub = l & 15;           // staging lane decomposition

  bf16x8 qf[2][4];
#pragma unroll
  for (int m = 0; m < 2; m++)
#pragma unroll
    for (int kk = 0; kk < 4; kk++)
      qf[m][kk] = *(const bf16x8*)(Qb + (long)(q0 + m * 64 + w * 16 + a) * HDv + kk * 32 + g * 8);

  f32x4 acc_o[2][8] = {};
  float m_run[2][4] = {{-1e30f, -1e30f, -1e30f, -1e30f}, {-1e30f, -1e30f, -1e30f, -1e30f}};
  float l_run[2][4] = {};
  const float scale = 0.08838834764831845f;  // 1/sqrt(128)
  const int kbmax = 2 * qb + 1;

  // stage one 64-key tile: K rows + packed V^T rows, pre-swizzled source (rule #21)
#define STAGE_TILE(kdst, vdst, kv0_)                                              \
  {                                                                               \
    _Pragma("unroll") for (int j = 0; j < 4; j++) {                               \
      int row = j * 16 + w * 4 + rr;                                              \
      int c0 = (sub * 8) ^ ((row & 15) << 3);                                     \
      GLL16(Kb + (long)((kv0_) + row) * HDv + c0, (kdst) + (j * 16 + w * 4) * 128); \
    }                                                                             \
    _Pragma("unroll") for (int j = 0; j < 4; j++) {                               \
      int row = w * 16 + j * 4 + rr;                                              \
      int c0 = (sub * 8) ^ ((row & 15) << 3);                                     \
      int d = row + (c0 & 64);                                                    \
      GLL16(VTb + (long)d * Sv + (kv0_) + (c0 & 63), (vdst) + (w * 16 + j * 4) * 128); \
    }                                                                             \
  }

  STAGE_TILE(k_s[0], vt_s[0], 0);              // prologue

  for (int kb = 0; kb <= kbmax; ++kb) {
    const int cur = kb & 1;
    const int kv0 = kb * 64;
    if (kb < kbmax) {
      STAGE_TILE(k_s[cur ^ 1], vt_s[cur ^ 1], kv0 + 64);
      asm volatile("s_waitcnt vmcnt(8)" ::: "memory");   // current tile landed; next 8 in flight
    } else {
      asm volatile("s_waitcnt vmcnt(0)" ::: "memory");
    }
    __builtin_amdgcn_s_barrier();
    __builtin_amdgcn_sched_barrier(0);
    const short* ks = k_s[cur];
    const short* vs = vt_s[cur];
#pragma unroll
    for (int m = 0; m < 2; m++) {
      if (m == 0 && kb == kbmax) continue;     // subtile 0 has no keys in last kb
      // ---- QK^T: S[16q][64k] ----
      f32x4 sacc[4] = {};
#pragma unroll
      for (int ksb = 0; ksb < 4; ksb++) {
        int row = ksb * 16 + a;
#pragma unroll
        for (int kk = 0; kk < 4; kk++) {
          bf16x8 kf = *(const bf16x8*)(ks + row * 128 + ((kk * 32 + g * 8) ^ ((row & 15) << 3)));
          sacc[ksb] = __builtin_amdgcn_mfma_f32_16x16x32_bf16(qf[m][kk], kf, sacc[ksb], 0, 0, 0);
        }
      }
      // ---- mask + online softmax (rows q = q0 + m*64 + w*16 + g*4 + r) ----
      const bool domask = (kb == 2 * qb + m);
      float s[4][4];
#pragma unroll
      for (int ksb = 0; ksb < 4; ksb++)
#pragma unroll
        for (int r = 0; r < 4; r++) {
          float v = sacc[ksb][r] * scale;
          if (domask) {
            int key = kv0 + ksb * 16 + a, qq = q0 + m * 64 + w * 16 + g * 4 + r;
            v = (key <= qq) ? v : -1e30f;
          }
          s[ksb][r] = v;
        }
      float mnew[4], alpha[4];
#pragma unroll
      for (int r = 0; r < 4; r++) {
        float mm = fmaxf(fmaxf(s[0][r], s[1][r]), fmaxf(s[2][r], s[3][r]));
        mm = fmaxf(mm, __shfl_xor(mm, 1));
        mm = fmaxf(mm, __shfl_xor(mm, 2));
        mm = fmaxf(mm, __shfl_xor(mm, 4));
        mm = fmaxf(mm, __shfl_xor(mm, 8));
        mnew[r] = fmaxf(m_run[m][r], mm);
        alpha[r] = __expf(m_run[m][r] - mnew[r]);
        m_run[m][r] = mnew[r];
      }
      float rs[4] = {0.f, 0.f, 0.f, 0.f};
#pragma unroll
      for (int ksb = 0; ksb < 4; ksb++)
#pragma unroll
        for (int r = 0; r < 4; r++) {
          float p = __expf(s[ksb][r] - mnew[r]);
          s[ksb][r] = p;
          rs[r] += p;
        }
#pragma unroll
      for (int r = 0; r < 4; r++) {
        float x = rs[r];
        x += __shfl_xor(x, 1);
        x += __shfl_xor(x, 2);
        x += __shfl_xor(x, 4);
        x += __shfl_xor(x, 8);
        l_run[m][r] = l_run[m][r] * alpha[r] + x;
      }
      // ---- P -> per-wave LDS (bf16, stride 64 + XOR), re-read in A-frag layout ----
#pragma unroll
      for (int ksb = 0; ksb < 4; ksb++)
#pragma unroll
        for (int r = 0; r < 4; r++) {
          int q_loc = g * 4 + r;
          p_s[w][m][q_loc * 64 + ((ksb * 16 + a) ^ ((q_loc & 7) << 3))] =
              (short)f2b(s[ksb][r]);
        }
      // ---- rescale O ----
#pragma unroll
      for (int d = 0; d < 8; d++)
#pragma unroll
        for (int r = 0; r < 4; r++) acc_o[m][d][r] *= alpha[r];
      // ---- PV: O += P[16q][64k] * V[64k][128d] via packed V^T ----
      bf16x8 pa[2];
#pragma unroll
      for (int kc = 0; kc < 2; kc++)
        pa[kc] = *(const bf16x8*)(&p_s[w][m][a * 64 + ((kc * 32 + g * 8) ^ ((a & 7) << 3))]);
#pragma unroll
      for (int dblk = 0; dblk < 8; dblk++) {
        int row = (dblk & 3) * 16 + a;         // packed row; half = dblk>>2
        int half = (dblk >> 2) * 64;
#pragma unroll
        for (int kc = 0; kc < 2; kc++) {
          bf16x8 vf = *(const bf16x8*)(vs + row * 128 +
                                       ((half + kc * 32 + g * 8) ^ ((row & 15) << 3)));
          acc_o[m][dblk] = __builtin_amdgcn_mfma_f32_16x16x32_bf16(pa[kc], vf, acc_o[m][dblk], 0, 0, 0);
        }
      }
    }
    __builtin_amdgcn_sched_barrier(0);
    __builtin_amdgcn_s_barrier();              // all waves done reading buf[cur]
  }
  // ---- epilogue: O /= l_run, write bf16 [B][S][D] ----
  const int b = bh >> 4, h = bh & 15;
#pragma unroll
  for (int m = 0; m < 2; m++)
#pragma unroll
    for (int r = 0; r < 4; r++) {
      float inv = 1.f / l_run[m][r];
      int q = q0 + m * 64 + w * 16 + g * 4 + r;
      short* orow = O + ((long)(b * Sv + q)) * Dv + h * HDv + a;
#pragma unroll
      for (int d = 0; d < 8; d++) orow[d * 16] = (short)f2b(acc_o[m][d][r] * inv);
    }
#undef STAGE_TILE
}

extern "C" void kernel_launch(void* const* d_in, const int* in_sizes, int n_in,
                              void* d_out, int out_size, void* d_ws, size_t ws_size,
                              hipStream_t stream) {
  // inputs: 0=hidden_states f32, 1=attention_mask (unused: deterministically causal),
  // 2=position_ids (unused: deterministically arange(S)), 3..6 = Wq,Wk,Wv,Wo f32 [K][N]
  const float* X = (const float*)d_in[0];
  const float* Wq = (const float*)d_in[3];
  const float* Wk = (const float*)d_in[4];
  const float* Wv = (const float*)d_in[5];
  const float* Wo = (const float*)d_in[6];
  float* out = (float*)d_out;

  // workspace layout (bf16 stored as short); AO aliases XB (XB dead after GEMM1);
  // VTG aliases WQKVT (dead after gemm<0>)
  short* XB = (short*)d_ws;              // 8,388,608 elems  [B*S][D] bf16
  short* WQKVT = XB + 8388608;           // 12,582,912       [3*D][K] bf16 (transposed)
  short* WOT = WQKVT + 12582912;         // 4,194,304        [D][K] bf16 (transposed)
  short* QKV = WOT + 4194304;            // 25,165,824       3 x [B][H][S][HD] bf16
  float* TAB = (float*)(QKV + 25165824); // 262,144 f32      [S][128] cos|sin
  short* AO = XB;                        // attn out [B][S][D] bf16 (reuse XB)
  short* VTG = WQKVT;                    // V^T [bh][d][key] (reuse WQKVT, 8.4M <= 12.6M)

  f2b_kernel<<<8192, 256, 0, stream>>>((const float4*)X, (ushort4*)XB, 2097152);
  dim3 wtb(32, 8), wtg(64, 64);
  wtrans_kernel<<<wtg, wtb, 0, stream>>>(Wq, WQKVT);
  wtrans_kernel<<<wtg, wtb, 0, stream>>>(Wk, WQKVT + 4194304);
  wtrans_kernel<<<wtg, wtb, 0, stream>>>(Wv, WQKVT + 8388608);
  wtrans_kernel<<<wtg, wtb, 0, stream>>>(Wo, WOT);
  rope_table_kernel<<<512, 256, 0, stream>>>(TAB);
  // QKV projection: M=4096, N=6144, K=2048 -> scatter to [3][B][H][S][HD]
  gemm_kernel<0><<<dim3(48, 32), 256, 0, stream>>>(XB, WQKVT, QKV, 4096, 6144, 2048);
  rope_kernel<<<4096, 256, 0, stream>>>(QKV, TAB);  // Q and K in one launch
  // V -> V^T (WQKVT region is dead after gemm<0>)
  vtrans_kernel<<<dim3(64, 4, 32), wtb, 0, stream>>>(QKV + 16777216, VTG);
  attn_kernel<<<dim3(16, 32), 256, 0, stream>>>(QKV, QKV + 8388608, VTG, AO);
  // output projection -> f32 d_out
  gemm_kernel<1><<<dim3(16, 32), 256, 0, stream>>>(AO, WOT, out, 4096, 2048, 2048);
}

// Round 10
// 481.352 us; speedup vs baseline: 1.4184x; 1.0646x over previous
//
#include <hip/hip_runtime.h>
#include <hip/hip_bf16.h>

// Problem constants (B=2, S=2048, D=2048, H=16, HD=128)
#define Bv 2
#define Sv 2048
#define Dv 2048
#define Hv 16
#define HDv 128

typedef short bf16x8 __attribute__((ext_vector_type(8)));
typedef float f32x4 __attribute__((ext_vector_type(4)));

__device__ inline float b2f(unsigned short u) {
  union { unsigned int i; float f; } x; x.i = ((unsigned int)u) << 16; return x.f;
}
__device__ inline unsigned short f2b(float f) {
  union { float f; unsigned int u; } x; x.f = f;
  unsigned int r = (x.u + 0x7fffu + ((x.u >> 16) & 1u)) >> 16;  // RNE
  return (unsigned short)r;
}

#define GLL16(gsrc, ldst)                                                      \
  __builtin_amdgcn_global_load_lds(                                            \
      (__attribute__((address_space(1))) void*)(gsrc),                         \
      (__attribute__((address_space(3))) void*)(ldst), 16, 0, 0)

// ---------------- f32 -> bf16 convert (vectorized) ----------------
__global__ __launch_bounds__(256) void f2b_kernel(const float4* __restrict__ in,
                                                  ushort4* __restrict__ out, int n4) {
  int i = blockIdx.x * 256 + threadIdx.x;
  if (i >= n4) return;
  float4 v = in[i];
  ushort4 r;
  r.x = f2b(v.x); r.y = f2b(v.y); r.z = f2b(v.z); r.w = f2b(v.w);
  out[i] = r;
}

// ---------------- W [K][N] f32 -> WT [N][K] bf16 (transpose-convert) ----------------
__global__ void wtrans_kernel(const float* __restrict__ W, short* __restrict__ WT) {
  __shared__ float tile[32][33];
  int tx = threadIdx.x, ty = threadIdx.y;        // 32 x 8
  int c0 = blockIdx.x * 32, r0 = blockIdx.y * 32;
#pragma unroll
  for (int i = 0; i < 4; i++)
    tile[ty + i * 8][tx] = W[(long)(r0 + ty + i * 8) * Dv + c0 + tx];
  __syncthreads();
#pragma unroll
  for (int i = 0; i < 4; i++)
    WT[(long)(c0 + ty + i * 8) * Dv + r0 + tx] = (short)f2b(tile[tx][ty + i * 8]);
}

// ---------------- RoPE cos/sin table: tab[s*128 + d]=cos, +64=sin (d<64) ----------------
__global__ __launch_bounds__(256) void rope_table_kernel(float* __restrict__ tab) {
  int i = blockIdx.x * 256 + threadIdx.x;  // 0 .. S*64-1
  int s = i >> 6, d = i & 63;
  float inv = powf(10000.f, -(float)d * (1.f / 64.f));
  float ang = (float)s * inv;
  tab[s * 128 + d] = cosf(ang);
  tab[s * 128 + 64 + d] = sinf(ang);
}

// ---------------- RoPE apply in-place on Q and K (contiguous, 2*B*H*S rows) ----------------
__global__ __launch_bounds__(256) void rope_kernel(short* __restrict__ T,
                                                   const float* __restrict__ tab) {
  int tid = blockIdx.x * 256 + threadIdx.x;   // 2*B*H*S*8 threads, 8 per row
  int r = tid >> 3, j = tid & 7;
  int s = r & (Sv - 1);
  short* p = T + (long)r * HDv + j * 8;
  bf16x8 a = *(const bf16x8*)p;
  bf16x8 bb = *(const bf16x8*)(p + 64);
  const float* tc = tab + s * 128 + j * 8;
  float4 c0 = *(const float4*)tc, c1 = *(const float4*)(tc + 4);
  float4 s0 = *(const float4*)(tc + 64), s1 = *(const float4*)(tc + 68);
  float cs[8] = {c0.x, c0.y, c0.z, c0.w, c1.x, c1.y, c1.z, c1.w};
  float sn[8] = {s0.x, s0.y, s0.z, s0.w, s1.x, s1.y, s1.z, s1.w};
  bf16x8 na, nb;
#pragma unroll
  for (int e = 0; e < 8; e++) {
    float x1 = b2f((unsigned short)a[e]);
    float x2 = b2f((unsigned short)bb[e]);
    na[e] = (short)f2b(x1 * cs[e] - x2 * sn[e]);
    nb[e] = (short)f2b(x2 * cs[e] + x1 * sn[e]);
  }
  *(bf16x8*)p = na;
  *(bf16x8*)(p + 64) = nb;
}

// ---------------- bf16 MFMA GEMM: C = A[M][K] * Bt[N][K]^T ----------------
// MODE 0: write bf16 QKV; Q,K scattered [B][H][S][HD]; V written TRANSPOSED [bh][d][s].
// MODE 1: write f32 row-major.
template <int MODE>
__global__ __launch_bounds__(256) void gemm_kernel(const short* __restrict__ A,
                                                   const short* __restrict__ Bt,
                                                   void* __restrict__ Cout,
                                                   int M, int N, int K) {
  __shared__ __align__(16) short As[128 * 32];
  __shared__ __align__(16) short Bs[128 * 32];
  const int t = threadIdx.x, w = t >> 6, l = t & 63;
  const int m0 = blockIdx.y * 128, n0 = blockIdx.x * 128;
  const int wr = w >> 1, wc = w & 1;
  f32x4 acc[4][4] = {};
  const short* ag = A + (long)(m0 + (t >> 2)) * K + (t & 3) * 8;
  const short* bg = Bt + (long)(n0 + (t >> 2)) * K + (t & 3) * 8;
  short* asw = As + (w * 16) * 32;   // wave-uniform LDS staging base
  short* bsw = Bs + (w * 16) * 32;
  const int aoff = (wr * 64 + (l & 15)) * 32 + (l >> 4) * 8;
  const int boff = (wc * 64 + (l & 15)) * 32 + (l >> 4) * 8;
  for (int k0 = 0; k0 < K; k0 += 32) {
    GLL16(ag + k0, asw);
    GLL16(ag + (long)64 * K + k0, asw + 64 * 32);
    GLL16(bg + k0, bsw);
    GLL16(bg + (long)64 * K + k0, bsw + 64 * 32);
    __syncthreads();
    bf16x8 af[4], bf[4];
#pragma unroll
    for (int i = 0; i < 4; i++) af[i] = *(const bf16x8*)(As + aoff + i * 16 * 32);
#pragma unroll
    for (int i = 0; i < 4; i++) bf[i] = *(const bf16x8*)(Bs + boff + i * 16 * 32);
#pragma unroll
    for (int i = 0; i < 4; i++)
#pragma unroll
      for (int j = 0; j < 4; j++)
        acc[i][j] = __builtin_amdgcn_mfma_f32_16x16x32_bf16(af[i], bf[j], acc[i][j], 0, 0, 0);
    __syncthreads();
  }
  // epilogue: C/D layout col = lane&15, row = (lane>>4)*4 + j  [m89-verified]
  const int fr = l >> 4;
#pragma unroll
  for (int mi = 0; mi < 4; mi++) {
#pragma unroll
    for (int ni = 0; ni < 4; ni++) {
      f32x4 v = acc[mi][ni];
      int col = n0 + wc * 64 + ni * 16 + (l & 15);
      int mbase = m0 + wr * 64 + mi * 16 + fr * 4;
      if (MODE == 0) {
        short* qkv = (short*)Cout;
        int which = col >> 11, hn = col & 2047;
        int h = hn >> 7, d = hn & 127;
#pragma unroll
        for (int j = 0; j < 4; j++) {
          int m = mbase + j;
          int b = m >> 11, s = m & 2047;
          if (which == 2) {  // V: write transposed [bh][d][key=s]
            qkv[(long)2 * 8388608 + ((long)(b * Hv + h) * HDv + d) * Sv + s] =
                (short)f2b(v[j]);
          } else {
            qkv[(long)which * 8388608 + (((long)(b * Hv + h)) * Sv + s) * HDv + d] =
                (short)f2b(v[j]);
          }
        }
      } else {
        float* C = (float*)Cout;
#pragma unroll
        for (int j = 0; j < 4; j++) C[(long)(mbase + j) * N + col] = v[j];
      }
    }
  }
}

// ---------------- MFMA flash attention, balanced-pair 2-phase pipelined ----------------
// 4 waves/block; wave owns 16 q-rows (QBLK=64). Each block serially processes TWO
// q-blocks {qbH=31-x, qbL=x} -> (32-x)+(x+1) = 33 tiles for EVERY block (perfect LPT).
// Double-buffered K + packed-V^T tiles; next tile's 8 GLL16 issue BEFORE compute,
// counted vmcnt(8) (never 0 mid-loop) + raw s_barrier. LDS 72 KB -> 2 blocks/CU.
__global__ __launch_bounds__(256, 2) void attn_kernel(const short* __restrict__ Q,
                                                      const short* __restrict__ Kk,
                                                      const short* __restrict__ VT,
                                                      short* __restrict__ O) {
  __shared__ __align__(16) short k_s[2][64 * 128];
  __shared__ __align__(16) short vt_s[2][64 * 128];
  __shared__ __align__(16) short p_s[4][16 * 64];
  const int tid = threadIdx.x, w = tid >> 6, l = tid & 63;
  const int g = l >> 4, a = l & 15;
  const int bh = blockIdx.y;
  const int x = blockIdx.x;            // pair id 0..15
  const int qbH = 31 - x, qbL = x;
  const int nb = 32 - x;               // tiles in heavy phase (kb = 0..qbH)
  const short* Qb = Q + (long)bh * Sv * HDv;
  const short* Kb = Kk + (long)bh * Sv * HDv;
  const short* VTb = VT + (long)bh * HDv * Sv;   // [d][key]
  const int rr = l >> 4, sub = l & 15;           // staging lane decomposition

  bf16x8 qfA[4], qfB[4];
#pragma unroll
  for (int kk = 0; kk < 4; kk++) {
    qfA[kk] = *(const bf16x8*)(Qb + (long)(qbH * 64 + w * 16 + a) * HDv + kk * 32 + g * 8);
    qfB[kk] = *(const bf16x8*)(Qb + (long)(qbL * 64 + w * 16 + a) * HDv + kk * 32 + g * 8);
  }

  f32x4 acc_o[8] = {};
  float m_run[4] = {-1e30f, -1e30f, -1e30f, -1e30f};
  float l_run[4] = {0.f, 0.f, 0.f, 0.f};
  int qcur = qbH;
  const float scale = 0.08838834764831845f;  // 1/sqrt(128)
  const int b = bh >> 4, h = bh & 15;

#define STAGE_TILE(kdst, vdst, kv0_)                                              \
  {                                                                               \
    _Pragma("unroll") for (int j = 0; j < 4; j++) {                               \
      int row = j * 16 + w * 4 + rr;                                              \
      int c0 = (sub * 8) ^ ((row & 15) << 3);                                     \
      GLL16(Kb + (long)((kv0_) + row) * HDv + c0, (kdst) + (j * 16 + w * 4) * 128); \
    }                                                                             \
    _Pragma("unroll") for (int j = 0; j < 4; j++) {                               \
      int row = w * 16 + j * 4 + rr;                                              \
      int c0 = (sub * 8) ^ ((row & 15) << 3);                                     \
      int d = row + (c0 & 64);                                                    \
      GLL16(VTb + (long)d * Sv + (kv0_) + (c0 & 63), (vdst) + (w * 16 + j * 4) * 128); \
    }                                                                             \
  }

#define WRITE_OUT(qbv)                                                            \
  {                                                                               \
    _Pragma("unroll") for (int r = 0; r < 4; r++) {                               \
      float inv = 1.f / l_run[r];                                                 \
      int q = (qbv) * 64 + w * 16 + g * 4 + r;                                    \
      short* orow = O + ((long)(b * Sv + q)) * Dv + h * HDv + a;                  \
      _Pragma("unroll") for (int d = 0; d < 8; d++)                               \
        orow[d * 16] = (short)f2b(acc_o[d][r] * inv);                             \
    }                                                                             \
  }

  STAGE_TILE(k_s[0], vt_s[0], 0);              // prologue: tile 0 (heavy kb=0)

  for (int t = 0; t <= 32; ++t) {
    const int cur = t & 1;
    const int kv0 = (t < nb) ? t * 64 : (t - nb) * 64;
    if (t < 32) {
      const int nk = ((t + 1) < nb) ? (t + 1) * 64 : (t + 1 - nb) * 64;
      STAGE_TILE(k_s[cur ^ 1], vt_s[cur ^ 1], nk);
      asm volatile("s_waitcnt vmcnt(8)" ::: "memory");   // tile t landed; t+1 in flight
    } else {
      asm volatile("s_waitcnt vmcnt(0)" ::: "memory");
    }
    __builtin_amdgcn_s_barrier();
    __builtin_amdgcn_sched_barrier(0);
    if (t == nb) {                             // heavy phase done: flush, reset, swap Q
      WRITE_OUT(qbH);
#pragma unroll
      for (int kk = 0; kk < 4; kk++) qfA[kk] = qfB[kk];
#pragma unroll
      for (int d = 0; d < 8; d++) acc_o[d] = (f32x4){0.f, 0.f, 0.f, 0.f};
#pragma unroll
      for (int r = 0; r < 4; r++) { m_run[r] = -1e30f; l_run[r] = 0.f; }
      qcur = qbL;
    }
    const short* ks = k_s[cur];
    const short* vs = vt_s[cur];
    // ---- QK^T: S[16q][64k] ----
    f32x4 sacc[4] = {};
#pragma unroll
    for (int ksb = 0; ksb < 4; ksb++) {
      int row = ksb * 16 + a;
#pragma unroll
      for (int kk = 0; kk < 4; kk++) {
        bf16x8 kf = *(const bf16x8*)(ks + row * 128 + ((kk * 32 + g * 8) ^ ((row & 15) << 3)));
        sacc[ksb] = __builtin_amdgcn_mfma_f32_16x16x32_bf16(qfA[kk], kf, sacc[ksb], 0, 0, 0);
      }
    }
    // ---- mask + online softmax (rows q = qcur*64 + w*16 + g*4 + r) ----
    const bool domask = (t == nb - 1) || (t == 32);
    float s[4][4];
#pragma unroll
    for (int ksb = 0; ksb < 4; ksb++)
#pragma unroll
      for (int r = 0; r < 4; r++) {
        float v = sacc[ksb][r] * scale;
        if (domask) {
          int key = kv0 + ksb * 16 + a, qq = qcur * 64 + w * 16 + g * 4 + r;
          v = (key <= qq) ? v : -1e30f;
        }
        s[ksb][r] = v;
      }
    float mnew[4], alpha[4];
#pragma unroll
    for (int r = 0; r < 4; r++) {
      float mm = fmaxf(fmaxf(s[0][r], s[1][r]), fmaxf(s[2][r], s[3][r]));
      mm = fmaxf(mm, __shfl_xor(mm, 1));
      mm = fmaxf(mm, __shfl_xor(mm, 2));
      mm = fmaxf(mm, __shfl_xor(mm, 4));
      mm = fmaxf(mm, __shfl_xor(mm, 8));
      mnew[r] = fmaxf(m_run[r], mm);
      alpha[r] = __expf(m_run[r] - mnew[r]);
      m_run[r] = mnew[r];
    }
    float rs[4] = {0.f, 0.f, 0.f, 0.f};
#pragma unroll
    for (int ksb = 0; ksb < 4; ksb++)
#pragma unroll
      for (int r = 0; r < 4; r++) {
        float p = __expf(s[ksb][r] - mnew[r]);
        s[ksb][r] = p;
        rs[r] += p;
      }
#pragma unroll
    for (int r = 0; r < 4; r++) {
      float xx = rs[r];
      xx += __shfl_xor(xx, 1);
      xx += __shfl_xor(xx, 2);
      xx += __shfl_xor(xx, 4);
      xx += __shfl_xor(xx, 8);
      l_run[r] = l_run[r] * alpha[r] + xx;
    }
    // ---- P -> per-wave LDS (bf16, stride 64 + XOR), re-read in A-frag layout ----
#pragma unroll
    for (int ksb = 0; ksb < 4; ksb++)
#pragma unroll
      for (int r = 0; r < 4; r++) {
        int q_loc = g * 4 + r;
        p_s[w][q_loc * 64 + ((ksb * 16 + a) ^ ((q_loc & 7) << 3))] = (short)f2b(s[ksb][r]);
      }
    // ---- rescale O ----
#pragma unroll
    for (int d = 0; d < 8; d++)
#pragma unroll
      for (int r = 0; r < 4; r++) acc_o[d][r] *= alpha[r];
    // ---- PV: O += P[16q][64k] * V[64k][128d] via packed V^T ----
    bf16x8 pa[2];
#pragma unroll
    for (int kc = 0; kc < 2; kc++)
      pa[kc] = *(const bf16x8*)(&p_s[w][a * 64 + ((kc * 32 + g * 8) ^ ((a & 7) << 3))]);
#pragma unroll
    for (int dblk = 0; dblk < 8; dblk++) {
      int row = (dblk & 3) * 16 + a;           // packed row; half = dblk>>2
      int half = (dblk >> 2) * 64;
#pragma unroll
      for (int kc = 0; kc < 2; kc++) {
        bf16x8 vf = *(const bf16x8*)(vs + row * 128 +
                                     ((half + kc * 32 + g * 8) ^ ((row & 15) << 3)));
        acc_o[dblk] = __builtin_amdgcn_mfma_f32_16x16x32_bf16(pa[kc], vf, acc_o[dblk], 0, 0, 0);
      }
    }
    __builtin_amdgcn_sched_barrier(0);
    __builtin_amdgcn_s_barrier();              // all waves done reading buf[cur]
  }
  WRITE_OUT(qbL);
#undef STAGE_TILE
#undef WRITE_OUT
}

extern "C" void kernel_launch(void* const* d_in, const int* in_sizes, int n_in,
                              void* d_out, int out_size, void* d_ws, size_t ws_size,
                              hipStream_t stream) {
  // inputs: 0=hidden_states f32, 1=attention_mask (unused: deterministically causal),
  // 2=position_ids (unused: deterministically arange(S)), 3..6 = Wq,Wk,Wv,Wo f32 [K][N]
  const float* X = (const float*)d_in[0];
  const float* Wq = (const float*)d_in[3];
  const float* Wk = (const float*)d_in[4];
  const float* Wv = (const float*)d_in[5];
  const float* Wo = (const float*)d_in[6];
  float* out = (float*)d_out;

  // workspace layout (bf16 stored as short); AO aliases XB (XB dead after GEMM1).
  // QKV V-region holds V ALREADY TRANSPOSED [bh][d][s] (written by gemm<0> epilogue).
  short* XB = (short*)d_ws;              // 8,388,608 elems  [B*S][D] bf16
  short* WQKVT = XB + 8388608;           // 12,582,912       [3*D][K] bf16 (transposed)
  short* WOT = WQKVT + 12582912;         // 4,194,304        [D][K] bf16 (transposed)
  short* QKV = WOT + 4194304;            // 25,165,824       Q,K [B][H][S][HD]; V^T [bh][d][s]
  float* TAB = (float*)(QKV + 25165824); // 262,144 f32      [S][128] cos|sin
  short* AO = XB;                        // attn out [B][S][D] bf16 (reuse XB)

  f2b_kernel<<<8192, 256, 0, stream>>>((const float4*)X, (ushort4*)XB, 2097152);
  dim3 wtb(32, 8), wtg(64, 64);
  wtrans_kernel<<<wtg, wtb, 0, stream>>>(Wq, WQKVT);
  wtrans_kernel<<<wtg, wtb, 0, stream>>>(Wk, WQKVT + 4194304);
  wtrans_kernel<<<wtg, wtb, 0, stream>>>(Wv, WQKVT + 8388608);
  wtrans_kernel<<<wtg, wtb, 0, stream>>>(Wo, WOT);
  rope_table_kernel<<<512, 256, 0, stream>>>(TAB);
  // QKV projection: M=4096, N=6144, K=2048 -> Q,K scatter + V transposed write
  gemm_kernel<0><<<dim3(48, 32), 256, 0, stream>>>(XB, WQKVT, QKV, 4096, 6144, 2048);
  rope_kernel<<<4096, 256, 0, stream>>>(QKV, TAB);  // Q and K in one launch
  attn_kernel<<<dim3(16, 32), 256, 0, stream>>>(QKV, QKV + 8388608, QKV + 16777216, AO);
  // output projection -> f32 d_out
  gemm_kernel<1><<<dim3(16, 32), 256, 0, stream>>>(AO, WOT, out, 4096, 2048, 2048);
}